// Round 1
// baseline (352.738 us; speedup 1.0000x reference)
//
#include <hip/hip_runtime.h>
#include <math.h>

#define TOPK 2048
#define NCLS_PAD 128   // classes are 0..79; pad for safety

// ---------------------------------------------------------------------------
// init: zero rank[] and class counts (ws is re-poisoned to 0xAA every call)
// ---------------------------------------------------------------------------
__global__ void k_init(unsigned int* rank, int M, int* ccount) {
    int i = blockIdx.x * blockDim.x + threadIdx.x;
    if (i < M) rank[i] = 0u;
    if (i < NCLS_PAD) ccount[i] = 0;
}

// ---------------------------------------------------------------------------
// build sort keys: monotonic float bits in high 32, (0xFFFFFFFF - i) low 32.
// Descending key order == descending score, ties -> lower index first
// (matches jax.lax.top_k stable semantics). Keys are globally unique.
// ---------------------------------------------------------------------------
__global__ void k_keys(const float* scores, int M, unsigned long long* keys) {
    int i = blockIdx.x * blockDim.x + threadIdx.x;
    if (i >= M) return;
    union { float f; unsigned int u; } cv;
    cv.f = scores[i];
    unsigned int bits = cv.u;
    bits = (bits & 0x80000000u) ? ~bits : (bits | 0x80000000u);
    keys[i] = ((unsigned long long)bits << 32) |
              (unsigned long long)(0xFFFFFFFFu - (unsigned int)i);
}

// ---------------------------------------------------------------------------
// rank[i] = #{ j : key_j > key_i }  (unique since keys unique)
// grid = (ceil(M/256), NJ); each block handles one j-chunk for 256 i's.
// ---------------------------------------------------------------------------
__global__ __launch_bounds__(256) void k_rank(const unsigned long long* keys, int M,
                                              int jchunk, unsigned int* rank) {
    __shared__ unsigned long long sk[256];
    int i = blockIdx.x * blockDim.x + threadIdx.x;
    unsigned long long ki = (i < M) ? keys[i] : 0xFFFFFFFFFFFFFFFFull;
    int j0 = blockIdx.y * jchunk;
    int j1 = j0 + jchunk; if (j1 > M) j1 = M;
    unsigned int cnt = 0;
    for (int base = j0; base < j1; base += 256) {
        int jn = j1 - base; if (jn > 256) jn = 256;
        __syncthreads();
        if ((int)threadIdx.x < jn) sk[threadIdx.x] = keys[base + threadIdx.x];
        __syncthreads();
        #pragma unroll 8
        for (int t = 0; t < jn; t++) cnt += (sk[t] > ki) ? 1u : 0u;
    }
    if (i < M && cnt) atomicAdd(&rank[i], cnt);
}

// ---------------------------------------------------------------------------
// scatter selected boxes to sorted positions; write boxes & classes outputs;
// compute per-box lambda MLP (5->16->1); build per-class index lists.
// ---------------------------------------------------------------------------
__global__ void k_scatter(const unsigned int* rank, int M, int K,
                          const float* boxes, const float* scores, const int* classes,
                          float* gx, float* gy, float* gw, float* gh, float* gs,
                          int* gcls, float* glam,
                          int* ccount, int* clist,
                          const float* lw1, const float* lb1,
                          const float* lw2, const float* lb2,
                          float* out_boxes, float* out_cls) {
    int i = blockIdx.x * blockDim.x + threadIdx.x;
    if (i >= M) return;
    unsigned int r = rank[i];
    if (r >= (unsigned int)K) return;
    float x = boxes[i * 4 + 0], y = boxes[i * 4 + 1];
    float w = boxes[i * 4 + 2], h = boxes[i * 4 + 3];
    float s = scores[i];
    int c = classes[i];
    gx[r] = x; gy[r] = y; gw[r] = w; gh[r] = h; gs[r] = s; gcls[r] = c;
    out_boxes[r * 4 + 0] = x; out_boxes[r * 4 + 1] = y;
    out_boxes[r * 4 + 2] = w; out_boxes[r * 4 + 3] = h;
    out_cls[r] = (float)c;
    // lambda MLP: relu([x,y,w,h,s] @ lw1(5x16) + lb1) @ lw2(16) + lb2 -> sigmoid
    float in5[5] = { x, y, w, h, s };
    float acc2 = lb2[0];
    #pragma unroll
    for (int o = 0; o < 16; o++) {
        float a = lb1[o];
        #pragma unroll
        for (int f = 0; f < 5; f++) a += in5[f] * lw1[f * 16 + o];
        a = fmaxf(a, 0.0f);
        acc2 += a * lw2[o];
    }
    glam[r] = 1.0f / (1.0f + expf(-acc2));
    int cc = (c >= 0 && c < NCLS_PAD) ? c : 0;
    int slot = atomicAdd(&ccount[cc], 1);
    clist[cc * K + slot] = (int)r;
}

// ---------------------------------------------------------------------------
// main: one block per row i.
//   Phase A: D_i = mean_j iou(i,j) over ALL j (unmasked).
//   Phase B: S_i = sum over same-class j of sigmoid(MLP(feats)) * iou.
//   out_scores[i] = s_i * exp(-lam_i * S_i * D_i)
// ---------------------------------------------------------------------------
__global__ __launch_bounds__(256) void k_main(int K,
        const float* gx, const float* gy, const float* gw, const float* gh,
        const float* gs, const int* gcls, const float* glam,
        const int* ccount, const int* clist,
        const float* w1, const float* b1, const float* w2, const float* b2,
        const float* w3, const float* b3,
        float* out_scores) {
    __shared__ float sx[TOPK], sy[TOPK], sww[TOPK], shh[TOPK], ssc[TOPK];
    __shared__ float swt[7 * 32 + 32 + 32 * 16 + 16 + 16 + 1]; // 801 floats
    __shared__ float red[256];
    int tid = threadIdx.x;
    for (int t = tid; t < K; t += 256) {
        sx[t] = gx[t]; sy[t] = gy[t]; sww[t] = gw[t]; shh[t] = gh[t]; ssc[t] = gs[t];
    }
    for (int t = tid; t < 224; t += 256) swt[t] = w1[t];
    if (tid < 32) swt[224 + tid] = b1[tid];
    for (int t = tid; t < 512; t += 256) swt[256 + t] = w2[t];
    if (tid < 16) swt[768 + tid] = b2[tid];
    if (tid < 16) swt[784 + tid] = w3[tid];
    if (tid == 0) swt[800] = b3[0];
    __syncthreads();

    const float* W1 = swt;
    const float* B1 = swt + 224;
    const float* W2 = swt + 256;
    const float* B2 = swt + 768;
    const float* W3 = swt + 784;
    const float  B3 = swt[800];

    int i = blockIdx.x;
    float xi = sx[i], yi = sy[i], wi = sww[i], hi = shh[i];
    float ai = wi * hi;
    float x2i = xi + wi, y2i = yi + hi;

    // Phase A: row mean of IoU
    float dsum = 0.0f;
    for (int j = tid; j < K; j += 256) {
        float xj = sx[j], yj = sy[j], wj = sww[j], hj = shh[j];
        float ix1 = fmaxf(xi, xj), iy1 = fmaxf(yi, yj);
        float ix2 = fminf(x2i, xj + wj), iy2 = fminf(y2i, yj + hj);
        float iw = fmaxf(ix2 - ix1, 0.0f), ih = fmaxf(iy2 - iy1, 0.0f);
        float inter = iw * ih;
        float uni = ai + wj * hj - inter;
        dsum += inter / (uni + 1e-6f);
    }
    red[tid] = dsum;
    __syncthreads();
    for (int s = 128; s > 0; s >>= 1) {
        if (tid < s) red[tid] += red[tid + s];
        __syncthreads();
    }
    float D = red[0] / (float)K;
    __syncthreads();

    // Phase B: masked suppression sum over same-class list
    float si = gs[i];
    int ci = gcls[i];
    int cb = (ci >= 0 && ci < NCLS_PAD) ? ci : 0;
    int cnt = ccount[cb];
    const int* lst = &clist[cb * K];
    float ssum = 0.0f;
    for (int t = tid; t < cnt; t += 256) {
        int j = lst[t];
        float xj = sx[j], yj = sy[j], wj = sww[j], hj = shh[j];
        float ix1 = fmaxf(xi, xj), iy1 = fmaxf(yi, yj);
        float ix2 = fminf(x2i, xj + wj), iy2 = fminf(y2i, yj + hj);
        float iw = fmaxf(ix2 - ix1, 0.0f), ih = fmaxf(iy2 - iy1, 0.0f);
        float inter = iw * ih;
        float uni = ai + wj * hj - inter;
        float iou = inter / (uni + 1e-6f);
        float f0 = iou;
        float f1 = fabsf(xi - xj), f2 = fabsf(yi - yj);
        float f3 = fabsf(wi - wj), f4 = fabsf(hi - hj);
        float f5 = si, f6 = ssc[j];
        float h1[32];
        #pragma unroll
        for (int o = 0; o < 32; o++) {
            float a = B1[o];
            a += f0 * W1[0 * 32 + o];
            a += f1 * W1[1 * 32 + o];
            a += f2 * W1[2 * 32 + o];
            a += f3 * W1[3 * 32 + o];
            a += f4 * W1[4 * 32 + o];
            a += f5 * W1[5 * 32 + o];
            a += f6 * W1[6 * 32 + o];
            h1[o] = fmaxf(a, 0.0f);
        }
        float acc3 = B3;
        #pragma unroll
        for (int p = 0; p < 16; p++) {
            float a = B2[p];
            #pragma unroll
            for (int o = 0; o < 32; o++) a += h1[o] * W2[o * 16 + p];
            acc3 += fmaxf(a, 0.0f) * W3[p];
        }
        float sij = 1.0f / (1.0f + expf(-acc3));
        ssum += sij * iou;
    }
    red[tid] = ssum;
    __syncthreads();
    for (int s = 128; s > 0; s >>= 1) {
        if (tid < s) red[tid] += red[tid + s];
        __syncthreads();
    }
    if (tid == 0) {
        float S = red[0];
        float E = glam[i] * S * D;
        out_scores[i] = si * expf(-E);
    }
}

extern "C" void kernel_launch(void* const* d_in, const int* in_sizes, int n_in,
                              void* d_out, int out_size, void* d_ws, size_t ws_size,
                              hipStream_t stream) {
    const float* boxes   = (const float*)d_in[0];
    const float* scores  = (const float*)d_in[1];
    const int*   classes = (const int*)d_in[2];
    const float* sw1 = (const float*)d_in[3];
    const float* sb1 = (const float*)d_in[4];
    const float* sw2 = (const float*)d_in[5];
    const float* sb2 = (const float*)d_in[6];
    const float* sw3 = (const float*)d_in[7];
    const float* sb3 = (const float*)d_in[8];
    const float* lw1 = (const float*)d_in[9];
    const float* lb1 = (const float*)d_in[10];
    const float* lw2 = (const float*)d_in[11];
    const float* lb2 = (const float*)d_in[12];

    int M = in_sizes[1];
    int K = (M < TOPK) ? M : TOPK;

    // workspace carve-up (all sizes kept 8B-aligned; M is even)
    char* ws = (char*)d_ws;
    unsigned long long* keys = (unsigned long long*)ws; ws += (size_t)M * 8;
    unsigned int* rank = (unsigned int*)ws;             ws += (size_t)M * 4;
    float* gx   = (float*)ws; ws += (size_t)K * 4;
    float* gy   = (float*)ws; ws += (size_t)K * 4;
    float* gw   = (float*)ws; ws += (size_t)K * 4;
    float* gh   = (float*)ws; ws += (size_t)K * 4;
    float* gs   = (float*)ws; ws += (size_t)K * 4;
    float* glam = (float*)ws; ws += (size_t)K * 4;
    int*   gcls = (int*)ws;   ws += (size_t)K * 4;
    int*   ccount = (int*)ws; ws += (size_t)NCLS_PAD * 4;
    int*   clist  = (int*)ws; ws += (size_t)NCLS_PAD * K * 4;

    float* out_boxes  = (float*)d_out;            // K*4
    float* out_scores = (float*)d_out + (size_t)K * 4;  // K
    float* out_cls    = (float*)d_out + (size_t)K * 5;  // K

    int mb = (M + 255) / 256;
    int ib = ((M > NCLS_PAD ? M : NCLS_PAD) + 255) / 256;

    k_init<<<ib, 256, 0, stream>>>(rank, M, ccount);
    k_keys<<<mb, 256, 0, stream>>>(scores, M, keys);

    const int NJ = 8;
    int jchunk = (M + NJ - 1) / NJ;
    k_rank<<<dim3(mb, NJ), 256, 0, stream>>>(keys, M, jchunk, rank);

    k_scatter<<<mb, 256, 0, stream>>>(rank, M, K, boxes, scores, classes,
                                      gx, gy, gw, gh, gs, gcls, glam,
                                      ccount, clist, lw1, lb1, lw2, lb2,
                                      out_boxes, out_cls);

    k_main<<<K, 256, 0, stream>>>(K, gx, gy, gw, gh, gs, gcls, glam,
                                  ccount, clist,
                                  sw1, sb1, sw2, sb2, sw3, sb3,
                                  out_scores);
}